// Round 3
// baseline (236.815 us; speedup 1.0000x reference)
//
#include <hip/hip_runtime.h>

#define NN 20000      // nodes
#define FIN 256
#define D1 1024       // H1*C1 = 8*128
#define NH 8
#define C2 128
#define CAP 64        // padded CSR bucket capacity (max degree ~35 incl. self-loop)

typedef unsigned short u16;
typedef unsigned char u8;
typedef __attribute__((ext_vector_type(8))) short bf16x8;
typedef __attribute__((ext_vector_type(4))) float f32x4;
typedef __attribute__((ext_vector_type(2))) float f32x2;

// ---------- bf16 helpers ----------
__device__ __forceinline__ float bf2f(u16 u) {
    return __uint_as_float(((unsigned int)u) << 16);
}
__device__ __forceinline__ u16 f2bf(float f) {
    unsigned int u = __float_as_uint(f);
    u += 0x7FFFu + ((u >> 16) & 1u);   // round-to-nearest-even
    return (u16)(u >> 16);
}
// ---------- fp8 e4m3 (OCP) helpers via HW converts ----------
__device__ __forceinline__ u8 f2fp8(float v) {
    int q = __builtin_amdgcn_cvt_pk_fp8_f32(v, v, 0, false);
    return (u8)(q & 0xFF);
}

// butterfly reductions: every lane ends with the result
__device__ __forceinline__ float bred_max(float v) {
    #pragma unroll
    for (int o = 32; o > 0; o >>= 1) v = fmaxf(v, __shfl_xor(v, o, 64));
    return v;
}
__device__ __forceinline__ float bred_sum(float v) {
    #pragma unroll
    for (int o = 32; o > 0; o >>= 1) v += __shfl_xor(v, o, 64);
    return v;
}

// async global->LDS, 16B per lane (global_load_lds_dwordx4)
typedef const __attribute__((address_space(1))) unsigned int* as1_u32p;
typedef __attribute__((address_space(3))) unsigned int* as3_u32p;
__device__ __forceinline__ void gload_lds16(const void* g, void* l) {
    __builtin_amdgcn_global_load_lds((as1_u32p)g, (as3_u32p)l, 16, 0, 0);
}

// ---------- fused prep: cast x->bf16 | transpose-cast W1 | W2 | init cnt ----------
// Block ranges: [0,5000) cast, [5000,5256) W1t, [5256,5384) W2t, [5384,...) cnt.
__global__ __launch_bounds__(256) void prep_kernel(const float* __restrict__ x,
                                                   u16* __restrict__ xb,
                                                   const float* __restrict__ W1,
                                                   u16* __restrict__ w1t,
                                                   const float* __restrict__ W2,
                                                   u16* __restrict__ w2t,
                                                   int* __restrict__ cnt) {
    __shared__ float tile[32][33];
    const int b = blockIdx.x, tid = threadIdx.x;
    if (b < 5000) {
        int i = (b * 256 + tid) * 4;
        if (i < NN * FIN) {
            float4 v = *(const float4*)(x + i);
            ushort4 o;
            o.x = f2bf(v.x); o.y = f2bf(v.y); o.z = f2bf(v.z); o.w = f2bf(v.w);
            *(ushort4*)(xb + i) = o;
        }
        return;
    }
    if (b < 5384) {
        const float* in; u16* out; int R, C, bx, by;
        if (b < 5256) {
            int q = b - 5000;                 // W1: [FIN x D1] -> [D1 x FIN]
            in = W1; out = w1t; R = FIN; C = D1;
            bx = (q & 31) * 32; by = (q >> 5) * 32;
        } else {
            int q = b - 5256;                 // W2: [D1 x C2] -> [C2 x D1]
            in = W2; out = w2t; R = D1; C = C2;
            bx = (q & 3) * 32; by = (q >> 2) * 32;
        }
        int tx = tid & 31, ty = tid >> 5;     // 32x8
        #pragma unroll
        for (int i = 0; i < 32; i += 8)
            tile[ty + i][tx] = in[(size_t)(by + ty + i) * C + bx + tx];
        __syncthreads();
        #pragma unroll
        for (int i = 0; i < 32; i += 8)
            out[(size_t)(bx + ty + i) * R + by + tx] = f2bf(tile[tx][ty + i]);
        return;
    }
    int i = (b - 5384) * 256 + tid;
    if (i < NN) cnt[i] = 0;
}

// ---------- bf16 MFMA GEMM (BK=32) with fused attention-score epilogue ----------
// C[MxN] = A[MxK] * Bt[NxK]^T.  Block col bj covers cols [bj*128,(bj+1)*128)
// = exactly one attention head, so each block computes COMPLETE per-row
// as/ad = sum_col h[row][col]*att[col] from its fp32 accumulators.
// OMODE 1: bf16 C out (layer 2; head=0, NHo=1)
// OMODE 2: fp8 e4m3 C out only (layer 1; head=blockIdx.y, NHo=8)
template <int BM, int OMODE>
__global__ __launch_bounds__(256) void gemm_mfma(const u16* __restrict__ A,
                                                 const u16* __restrict__ Bt,
                                                 void* __restrict__ C,
                                                 const float* __restrict__ attS,
                                                 const float* __restrict__ attD,
                                                 float* __restrict__ as_out,
                                                 float* __restrict__ ad_out,
                                                 int NHo,
                                                 int M, int N, int K) {
    constexpr int TM = BM / 32;            // 16-tiles per wave along m
    __shared__ u16 ldsA[BM * 32];
    __shared__ u16 ldsB[128 * 32];
    __shared__ float asb[BM], adb[BM];
    const int tid = threadIdx.x;
    const int lane = tid & 63, w = tid >> 6;
    const int wr = w >> 1, wc = w & 1;
    const int row0 = blockIdx.x * BM, col0 = blockIdx.y * 128;
    const int head = blockIdx.y;
    const int l15 = lane & 15, quad = lane >> 4;

    for (int t = tid; t < BM; t += 256) { asb[t] = 0.f; adb[t] = 0.f; }

    f32x4 acc[TM][4];
    #pragma unroll
    for (int i = 0; i < TM; i++)
        #pragma unroll
        for (int j = 0; j < 4; j++)
            acc[i][j] = (f32x4){0.f, 0.f, 0.f, 0.f};

    for (int k0 = 0; k0 < K; k0 += 32) {
        #pragma unroll
        for (int i = 0; i < BM / 64; i++) {
            int c = tid + i * 256;
            int r = c >> 2, ko = (c & 3) * 8;
            int gr = row0 + r; if (gr >= M) gr = M - 1;  // clamp: rows >=M never stored
            gload_lds16(A + (size_t)gr * K + k0 + ko, ldsA + c * 8);
        }
        #pragma unroll
        for (int i = 0; i < 2; i++) {
            int c = tid + i * 256;
            int n = c >> 2, ko = (c & 3) * 8;
            gload_lds16(Bt + (size_t)(col0 + n) * K + k0 + ko, ldsB + c * 8);
        }
        __syncthreads();
        bf16x8 af[TM], bfr[4];
        #pragma unroll
        for (int i = 0; i < TM; i++) {
            int m = wr * (BM / 2) + i * 16 + l15;
            af[i] = *(const bf16x8*)(ldsA + m * 32 + quad * 8);
        }
        #pragma unroll
        for (int j = 0; j < 4; j++) {
            int n = wc * 64 + j * 16 + l15;
            bfr[j] = *(const bf16x8*)(ldsB + n * 32 + quad * 8);
        }
        #pragma unroll
        for (int i = 0; i < TM; i++)
            #pragma unroll
            for (int j = 0; j < 4; j++)
                acc[i][j] = __builtin_amdgcn_mfma_f32_16x16x32_bf16(af[i], bfr[j], acc[i][j], 0, 0, 0);
        __syncthreads();
    }
    // ---- C write (fp8 for layer1, bf16 for layer2) ----
    #pragma unroll
    for (int i = 0; i < TM; i++) {
        #pragma unroll
        for (int j = 0; j < 4; j++) {
            #pragma unroll
            for (int r = 0; r < 4; r++) {
                int row = row0 + wr * (BM / 2) + i * 16 + quad * 4 + r;
                int col = col0 + wc * 64 + j * 16 + l15;
                if (row < M) {
                    float v = acc[i][j][r];
                    if (OMODE == 1)
                        ((u16*)C)[(size_t)row * N + col] = f2bf(v);
                    else
                        ((u8*)C)[(size_t)row * N + col] = f2fp8(v);
                }
            }
        }
    }
    // ---- fused per-row attention dots for this head ----
    float attS_r[4], attD_r[4];
    #pragma unroll
    for (int j = 0; j < 4; j++) {
        int col = wc * 64 + j * 16 + l15;
        attS_r[j] = attS[head * 128 + col];
        attD_r[j] = attD[head * 128 + col];
    }
    #pragma unroll
    for (int i = 0; i < TM; i++) {
        #pragma unroll
        for (int r = 0; r < 4; r++) {
            float ps = 0.f, pd = 0.f;
            #pragma unroll
            for (int j = 0; j < 4; j++) {
                float v = acc[i][j][r];
                ps = fmaf(v, attS_r[j], ps);
                pd = fmaf(v, attD_r[j], pd);
            }
            #pragma unroll
            for (int o = 1; o < 16; o <<= 1) {
                ps += __shfl_xor(ps, o, 64);
                pd += __shfl_xor(pd, o, 64);
            }
            if (l15 == 0) {
                int row = wr * (BM / 2) + i * 16 + quad * 4 + r;
                atomicAdd(&asb[row], ps);
                atomicAdd(&adb[row], pd);
            }
        }
    }
    __syncthreads();
    for (int t = tid; t < BM; t += 256) {
        int row = row0 + t;
        if (row < M) {
            as_out[(size_t)row * NHo + head] = asb[t];
            ad_out[(size_t)row * NHo + head] = adb[t];
        }
    }
}

// ---------- padded-bucket CSR fill + layer-1 edge weights (8 heads) ----------
__global__ void fill_kernel(const int* __restrict__ ei, int E, int N,
                            int* __restrict__ cnt,
                            int* __restrict__ csr,
                            const float* __restrict__ as1,
                            const float* __restrict__ ad1,
                            float* __restrict__ pw1) {
    int j = blockIdx.x * 256 + threadIdx.x;
    if (j >= E + N) return;
    int s, d;
    if (j < E) { s = ei[j]; d = ei[E + j]; }
    else { s = j - E; d = j - E; }
    int pos = atomicAdd(&cnt[d], 1);
    if (pos >= CAP) return;   // safety net (never expected)
    int slot = d * CAP + pos;
    csr[slot] = s;
    float4 s0 = *(const float4*)(as1 + s * NH);
    float4 s1 = *(const float4*)(as1 + s * NH + 4);
    float4 d0 = *(const float4*)(ad1 + d * NH);
    float4 d1 = *(const float4*)(ad1 + d * NH + 4);
    float e[8] = {s0.x + d0.x, s0.y + d0.y, s0.z + d0.z, s0.w + d0.w,
                  s1.x + d1.x, s1.y + d1.y, s1.z + d1.z, s1.w + d1.w};
    float p[8];
    #pragma unroll
    for (int h = 0; h < 8; h++) {
        float v = e[h] > 0.f ? e[h] : 0.2f * e[h];
        p[h] = __expf(v);
    }
    *(float4*)(pw1 + (size_t)slot * 8) = *(const float4*)p;
    *(float4*)(pw1 + (size_t)slot * 8 + 4) = *(const float4*)(p + 4);
}

// ---------- layer-1 softmax-aggregate + ELU ----------
// ONE WAVE per dst, padded bucket. GROUP=8 depth-2 ping-pong: 8 row-gathers
// + 8 weight loads in flight while 8 edges compute (~214ns VALU) -> covers
// the ~300-400ns L2/L3 latency (R2's 4-edge stages only hid ~110ns).
// Setup chain broken: csr is loaded UNCLAMPED at lane position (always
// in-bounds; only contents beyond deg are garbage) so csr and cnt loads
// issue in parallel. Garbage indices are range-clamped to [0,NN-1] after
// readlane (2 SALU) -> any clamped row holds real finite fp8 (all NN rows
// written by the GEMM; e4m3fn NaNs can't occur in-array). Pad-edge weights
// are cndmask'd to 0 BEFORE the FMA, so garbage rows contribute nothing.
// deg gates only the trip count and the weight mask - not the address path.
#define A1_FETCH8(E0, Q, P)                                                   \
    {                                                                         \
        _Pragma("unroll")                                                     \
        for (int u = 0; u < 8; u++) {                                         \
            int e = (E0) + u;             /* e <= 63 < CAP always */          \
            int s = __builtin_amdgcn_readlane(idx, e);                        \
            s = s < 0 ? 0 : (s > NN - 1 ? NN - 1 : s);   /* SALU clamp */     \
            Q[u] = *(const uint4*)(h1q + (size_t)s * D1 + c0);                \
            P[u] = pwc[e * 8];            /* raw; masked at PROC */           \
        }                                                                     \
        __builtin_amdgcn_sched_barrier(0);                                    \
    }
#define A1_PROC8(E0, Q, P)                                                    \
    {                                                                         \
        _Pragma("unroll")                                                     \
        for (int u = 0; u < 8; u++) {                                         \
            float pp = ((E0) + u < deg) ? (P)[u] : 0.f;                       \
            den += pp;                                                        \
            f32x2 pv2 = {pp, pp};                                             \
            acc[0] += pv2 * __builtin_amdgcn_cvt_pk_f32_fp8((Q)[u].x, false); \
            acc[1] += pv2 * __builtin_amdgcn_cvt_pk_f32_fp8((Q)[u].x, true);  \
            acc[2] += pv2 * __builtin_amdgcn_cvt_pk_f32_fp8((Q)[u].y, false); \
            acc[3] += pv2 * __builtin_amdgcn_cvt_pk_f32_fp8((Q)[u].y, true);  \
            acc[4] += pv2 * __builtin_amdgcn_cvt_pk_f32_fp8((Q)[u].z, false); \
            acc[5] += pv2 * __builtin_amdgcn_cvt_pk_f32_fp8((Q)[u].z, true);  \
            acc[6] += pv2 * __builtin_amdgcn_cvt_pk_f32_fp8((Q)[u].w, false); \
            acc[7] += pv2 * __builtin_amdgcn_cvt_pk_f32_fp8((Q)[u].w, true);  \
        }                                                                     \
    }

__global__ __launch_bounds__(256) void agg1_kernel(const u8* __restrict__ h1q,
                                                   const float* __restrict__ pw1,
                                                   const int* __restrict__ cnt,
                                                   const int* __restrict__ csr,
                                                   const float* __restrict__ bias1,
                                                   u16* __restrict__ x2) {
    const int tid = threadIdx.x;
    const int lane = tid & 63;
    const int dst = (blockIdx.x << 2) + (tid >> 6);
    const int c0 = lane * 16;               // 16 channels per lane
    const int h = lane >> 3;                // head
    const int base = dst * CAP;

    int idx = csr[base + lane];                     // UNCLAMPED: || with cnt load
    const int deg = __builtin_amdgcn_readfirstlane(max(1, min(cnt[dst], CAP)));
    const float* pwc = pw1 + (size_t)base * 8 + h;  // per-lane head plane

    f32x2 acc[8];
    #pragma unroll
    for (int k = 0; k < 8; k++) acc[k] = (f32x2){0.f, 0.f};
    float den = 0.f;

    const int nit = (deg + 7) >> 3;                 // groups of 8
    uint4 qa[8], qb[8];
    float pa[8], pb[8];
    A1_FETCH8(0, qa, pa)
    int g = 0;
    for (; g + 2 < nit; g += 2) {                   // ping-pong
        A1_FETCH8((g + 1) * 8, qb, pb)
        A1_PROC8(g * 8, qa, pa)
        A1_FETCH8((g + 2) * 8, qa, pa)
        A1_PROC8((g + 1) * 8, qb, pb)
    }
    if (g + 1 < nit) {
        A1_FETCH8((g + 1) * 8, qb, pb)
        A1_PROC8(g * 8, qa, pa)
        A1_PROC8((g + 1) * 8, qb, pb)
    } else {
        A1_PROC8(g * 8, qa, pa)
    }

    float inv = 1.f / (den + 1e-16f);
    u16 ov[16];
    #pragma unroll
    for (int k = 0; k < 8; k++) {
        float a0 = acc[k][0] * inv + bias1[c0 + 2 * k];
        float a1 = acc[k][1] * inv + bias1[c0 + 2 * k + 1];
        a0 = a0 > 0.f ? a0 : (__expf(a0) - 1.f);   // ELU (abs err ~1e-7, tol 0.03)
        a1 = a1 > 0.f ? a1 : (__expf(a1) - 1.f);
        ov[2 * k] = f2bf(a0);
        ov[2 * k + 1] = f2bf(a1);
    }
    *(uint4*)(x2 + (size_t)dst * D1 + c0) = *(const uint4*)ov;
    *(uint4*)(x2 + (size_t)dst * D1 + c0 + 8) = *(const uint4*)(ov + 8);
}

// ---------- layer-2 softmax-aggregate + log_softmax (inline edge weights) ----------
// ONE WAVE per dst; same GROUP=8 depth-2 ping-pong + parallel setup loads.
// pl computed unconditionally (clamped idx -> finite as2 row); pad-edge
// mask applied at PROC via scalar (e<deg) select, off the exp chain.
#define A2_FETCH8(E0, Q)                                                      \
    {                                                                         \
        _Pragma("unroll")                                                     \
        for (int u = 0; u < 8; u++) {                                         \
            int s = __builtin_amdgcn_readlane(idx, (E0) + u);                 \
            s = s < 0 ? 0 : (s > NN - 1 ? NN - 1 : s);                        \
            Q[u] = *(const unsigned int*)(h2 + (size_t)s * C2 + lane2);       \
        }                                                                     \
        __builtin_amdgcn_sched_barrier(0);                                    \
    }
#define A2_PROC8(E0, Q)                                                       \
    {                                                                         \
        _Pragma("unroll")                                                     \
        for (int u = 0; u < 8; u++) {                                         \
            int e = (E0) + u;                                                 \
            float pp = (e < deg) ? __uint_as_float(__builtin_amdgcn_readlane( \
                                       __float_as_uint(pl), e))               \
                                 : 0.f;                                       \
            den += pp;                                                        \
            f32x2 pv2 = {pp, pp};                                             \
            f32x2 f = {__uint_as_float((Q)[u] << 16),                         \
                       __uint_as_float((Q)[u] & 0xFFFF0000u)};                \
            acc += pv2 * f;                                                   \
        }                                                                     \
    }

__global__ __launch_bounds__(256) void agg2_kernel(const u16* __restrict__ h2,
                                                   const float* __restrict__ as2,
                                                   const float* __restrict__ ad2,
                                                   const int* __restrict__ cnt,
                                                   const int* __restrict__ csr,
                                                   const float* __restrict__ bias2,
                                                   float* __restrict__ out) {
    const int tid = threadIdx.x;
    const int lane = tid & 63;
    const int dst = (blockIdx.x << 2) + (tid >> 6);
    const int base = dst * CAP;
    const int lane2 = lane * 2;

    int idx = csr[base + lane];                 // UNCLAMPED: || with cnt load
    const int deg = __builtin_amdgcn_readfirstlane(max(1, min(cnt[dst], CAP)));
    const float adv = ad2[dst];
    int idxc = idx < 0 ? 0 : (idx > NN - 1 ? NN - 1 : idx);
    float ev = as2[idxc] + adv;                 // random 4B within 80 KB (L2-hit)
    ev = ev > 0.f ? ev : 0.2f * ev;
    float pl = __expf(ev);                      // finite for any in-range row

    f32x2 acc = {0.f, 0.f};
    float den = 0.f;

    const int nit = (deg + 7) >> 3;
    unsigned int qa[8], qb[8];
    A2_FETCH8(0, qa)
    int g = 0;
    for (; g + 2 < nit; g += 2) {
        A2_FETCH8((g + 1) * 8, qb)
        A2_PROC8(g * 8, qa)
        A2_FETCH8((g + 2) * 8, qa)
        A2_PROC8((g + 1) * 8, qb)
    }
    if (g + 1 < nit) {
        A2_FETCH8((g + 1) * 8, qb)
        A2_PROC8(g * 8, qa)
        A2_PROC8((g + 1) * 8, qb)
    } else {
        A2_PROC8(g * 8, qa)
    }

    float inv = 1.f / (den + 1e-16f);
    float l0 = acc[0] * inv + bias2[lane2];
    float l1 = acc[1] * inv + bias2[lane2 + 1];
    // log_softmax over the wave's 128 channels
    float m = bred_max(fmaxf(l0, l1));
    float ex = bred_sum(__expf(l0 - m) + __expf(l1 - m));
    float lse = m + __logf(ex);
    float2 ov = {l0 - lse, l1 - lse};
    *(float2*)(out + (size_t)dst * C2 + lane2) = ov;
}

extern "C" void kernel_launch(void* const* d_in, const int* in_sizes, int n_in,
                              void* d_out, int out_size, void* d_ws, size_t ws_size,
                              hipStream_t stream) {
    const float* x        = (const float*)d_in[0];
    const int*   ei       = (const int*)d_in[1];
    const float* W1       = (const float*)d_in[2];
    const float* att_src1 = (const float*)d_in[3];
    const float* att_dst1 = (const float*)d_in[4];
    const float* bias1    = (const float*)d_in[5];
    const float* W2       = (const float*)d_in[6];
    const float* att_src2 = (const float*)d_in[7];
    const float* att_dst2 = (const float*)d_in[8];
    const float* bias2    = (const float*)d_in[9];
    float* out = (float*)d_out;
    const int E = in_sizes[1] / 2;

    char* ws = (char*)d_ws;
    size_t off = 0;
    auto alloc = [&](size_t b) {
        void* p = ws + off;
        off += (b + 255) & ~(size_t)255;
        return p;
    };
    u8*  h1q  = (u8*)alloc((size_t)NN * D1);
    u16* x2   = (u16*)alloc((size_t)NN * D1 * 2);
    u16* h2   = (u16*)alloc((size_t)NN * C2 * 2);
    u16* xb   = (u16*)alloc((size_t)NN * FIN * 2);
    u16* w1t  = (u16*)alloc((size_t)D1 * FIN * 2);
    u16* w2t  = (u16*)alloc((size_t)C2 * D1 * 2);
    float* as1 = (float*)alloc((size_t)NN * NH * 4);
    float* ad1 = (float*)alloc((size_t)NN * NH * 4);
    float* as2 = (float*)alloc((size_t)NN * 4);
    float* ad2 = (float*)alloc((size_t)NN * 4);
    int* cnt  = (int*)alloc((size_t)NN * 4);
    int* csr  = (int*)alloc((size_t)NN * CAP * 4);
    float* pw1 = (float*)alloc((size_t)NN * CAP * 8 * 4);

    // fused prep: cast x, transpose W1/W2, zero cnt
    const int PREP_BLOCKS = 5000 + 256 + 128 + (NN + 255) / 256;
    prep_kernel<<<PREP_BLOCKS, 256, 0, stream>>>(x, xb, W1, w1t, W2, w2t, cnt);

    // layer 1 GEMM: h1q fp8 + fused per-head as1/ad1
    gemm_mfma<128, 2><<<dim3((NN + 127) / 128, D1 / 128), 256, 0, stream>>>(
        xb, w1t, h1q, att_src1, att_dst1, as1, ad1, NH, NN, D1, FIN);
    fill_kernel<<<(E + NN + 255) / 256, 256, 0, stream>>>(ei, E, NN, cnt, csr,
                                                          as1, ad1, pw1);
    // 1 wave per dst: 20000 waves = 5000 blocks
    agg1_kernel<<<(NN + 3) / 4, 256, 0, stream>>>(h1q, pw1, cnt, csr, bias1, x2);
    // layer 2 GEMM: h2 bf16 + fused as2/ad2
    gemm_mfma<64, 1><<<dim3((NN + 63) / 64, C2 / 128), 256, 0, stream>>>(
        x2, w2t, h2, att_src2, att_dst2, as2, ad2, 1, NN, C2, D1);
    agg2_kernel<<<(NN + 3) / 4, 256, 0, stream>>>(h2, as2, ad2, cnt, csr, bias2, out);
}

// Round 4
// 231.173 us; speedup vs baseline: 1.0244x; 1.0244x over previous
//
#include <hip/hip_runtime.h>

#define NN 20000      // nodes
#define FIN 256
#define D1 1024       // H1*C1 = 8*128
#define NH 8
#define C2 128
#define CAP 64        // padded CSR bucket capacity (max degree ~35 incl. self-loop)

typedef unsigned short u16;
typedef unsigned char u8;
typedef __attribute__((ext_vector_type(8))) short bf16x8;
typedef __attribute__((ext_vector_type(4))) float f32x4;
typedef __attribute__((ext_vector_type(2))) float f32x2;

// ---------- bf16 helpers ----------
__device__ __forceinline__ float bf2f(u16 u) {
    return __uint_as_float(((unsigned int)u) << 16);
}
__device__ __forceinline__ u16 f2bf(float f) {
    unsigned int u = __float_as_uint(f);
    u += 0x7FFFu + ((u >> 16) & 1u);   // round-to-nearest-even
    return (u16)(u >> 16);
}
// ---------- fp8 e4m3 (OCP) helpers via HW converts ----------
__device__ __forceinline__ u8 f2fp8(float v) {
    int q = __builtin_amdgcn_cvt_pk_fp8_f32(v, v, 0, false);
    return (u8)(q & 0xFF);
}

// butterfly reductions: every lane ends with the result
__device__ __forceinline__ float bred_max(float v) {
    #pragma unroll
    for (int o = 32; o > 0; o >>= 1) v = fmaxf(v, __shfl_xor(v, o, 64));
    return v;
}
__device__ __forceinline__ float bred_sum(float v) {
    #pragma unroll
    for (int o = 32; o > 0; o >>= 1) v += __shfl_xor(v, o, 64);
    return v;
}

// async global->LDS, 16B per lane (global_load_lds_dwordx4)
typedef const __attribute__((address_space(1))) unsigned int* as1_u32p;
typedef __attribute__((address_space(3))) unsigned int* as3_u32p;
__device__ __forceinline__ void gload_lds16(const void* g, void* l) {
    __builtin_amdgcn_global_load_lds((as1_u32p)g, (as3_u32p)l, 16, 0, 0);
}

// ---------- fused prep: cast x->bf16 | transpose-cast W1 | W2 | init cnt ----------
// Block ranges: [0,5000) cast, [5000,5256) W1t, [5256,5384) W2t, [5384,...) cnt.
__global__ __launch_bounds__(256) void prep_kernel(const float* __restrict__ x,
                                                   u16* __restrict__ xb,
                                                   const float* __restrict__ W1,
                                                   u16* __restrict__ w1t,
                                                   const float* __restrict__ W2,
                                                   u16* __restrict__ w2t,
                                                   int* __restrict__ cnt) {
    __shared__ float tile[32][33];
    const int b = blockIdx.x, tid = threadIdx.x;
    if (b < 5000) {
        int i = (b * 256 + tid) * 4;
        if (i < NN * FIN) {
            float4 v = *(const float4*)(x + i);
            ushort4 o;
            o.x = f2bf(v.x); o.y = f2bf(v.y); o.z = f2bf(v.z); o.w = f2bf(v.w);
            *(ushort4*)(xb + i) = o;
        }
        return;
    }
    if (b < 5384) {
        const float* in; u16* out; int R, C, bx, by;
        if (b < 5256) {
            int q = b - 5000;                 // W1: [FIN x D1] -> [D1 x FIN]
            in = W1; out = w1t; R = FIN; C = D1;
            bx = (q & 31) * 32; by = (q >> 5) * 32;
        } else {
            int q = b - 5256;                 // W2: [D1 x C2] -> [C2 x D1]
            in = W2; out = w2t; R = D1; C = C2;
            bx = (q & 3) * 32; by = (q >> 2) * 32;
        }
        int tx = tid & 31, ty = tid >> 5;     // 32x8
        #pragma unroll
        for (int i = 0; i < 32; i += 8)
            tile[ty + i][tx] = in[(size_t)(by + ty + i) * C + bx + tx];
        __syncthreads();
        #pragma unroll
        for (int i = 0; i < 32; i += 8)
            out[(size_t)(bx + ty + i) * R + by + tx] = f2bf(tile[tx][ty + i]);
        return;
    }
    int i = (b - 5384) * 256 + tid;
    if (i < NN) cnt[i] = 0;
}

// ---------- bf16 MFMA GEMM, 2-phase double-buffered (T3-minimum) ----------
// C[MxN] = A[MxK] * Bt[NxK]^T.  Per K-step: issue next tile's
// global_load_lds into buf^1, then ds_read+MFMA on buf, then ONE
// __syncthreads (vmcnt drain had the compute phase to overlap).
// Replaces the old stage->barrier->compute->barrier (2 barriers, zero
// overlap). Fused per-head attention-dot epilogue unchanged.
// OMODE 1: bf16 C out (layer 2); OMODE 2: fp8 e4m3 C out (layer 1).
#define G_STAGE(BUF, K0)                                                   \
    {                                                                      \
        _Pragma("unroll")                                                  \
        for (int i = 0; i < BM / 64; i++) {                                \
            int c = tid + i * 256;                                         \
            int r = c >> 2, ko = (c & 3) * 8;                              \
            int gr = row0 + r; if (gr >= M) gr = M - 1;                    \
            gload_lds16(A + (size_t)gr * K + (K0) + ko,                    \
                        &ldsA[BUF][c * 8]);                                \
        }                                                                  \
        _Pragma("unroll")                                                  \
        for (int i = 0; i < 2; i++) {                                      \
            int c = tid + i * 256;                                         \
            int n = c >> 2, ko = (c & 3) * 8;                              \
            gload_lds16(Bt + (size_t)(col0 + n) * K + (K0) + ko,           \
                        &ldsB[BUF][c * 8]);                                \
        }                                                                  \
    }

template <int BM, int OMODE>
__global__ __launch_bounds__(256) void gemm_mfma(const u16* __restrict__ A,
                                                 const u16* __restrict__ Bt,
                                                 void* __restrict__ C,
                                                 const float* __restrict__ attS,
                                                 const float* __restrict__ attD,
                                                 float* __restrict__ as_out,
                                                 float* __restrict__ ad_out,
                                                 int NHo,
                                                 int M, int N, int K) {
    constexpr int TM = BM / 32;            // 16-tiles per wave along m
    __shared__ u16 ldsA[2][BM * 32];
    __shared__ u16 ldsB[2][128 * 32];
    __shared__ float asb[BM], adb[BM];
    const int tid = threadIdx.x;
    const int lane = tid & 63, w = tid >> 6;
    const int wr = w >> 1, wc = w & 1;
    const int row0 = blockIdx.x * BM, col0 = blockIdx.y * 128;
    const int head = blockIdx.y;
    const int l15 = lane & 15, quad = lane >> 4;

    for (int t = tid; t < BM; t += 256) { asb[t] = 0.f; adb[t] = 0.f; }

    f32x4 acc[TM][4];
    #pragma unroll
    for (int i = 0; i < TM; i++)
        #pragma unroll
        for (int j = 0; j < 4; j++)
            acc[i][j] = (f32x4){0.f, 0.f, 0.f, 0.f};

    G_STAGE(0, 0)
    __syncthreads();
    int cur = 0;
    for (int k0 = 0; k0 < K; k0 += 32) {
        if (k0 + 32 < K) {
            G_STAGE(cur ^ 1, k0 + 32)              // prefetch next K-tile
            __builtin_amdgcn_sched_barrier(0);     // keep issue above compute
        }
        bf16x8 af[TM], bfr[4];
        #pragma unroll
        for (int i = 0; i < TM; i++) {
            int m = wr * (BM / 2) + i * 16 + l15;
            af[i] = *(const bf16x8*)(&ldsA[cur][m * 32 + quad * 8]);
        }
        #pragma unroll
        for (int j = 0; j < 4; j++) {
            int n = wc * 64 + j * 16 + l15;
            bfr[j] = *(const bf16x8*)(&ldsB[cur][n * 32 + quad * 8]);
        }
        #pragma unroll
        for (int i = 0; i < TM; i++)
            #pragma unroll
            for (int j = 0; j < 4; j++)
                acc[i][j] = __builtin_amdgcn_mfma_f32_16x16x32_bf16(af[i], bfr[j], acc[i][j], 0, 0, 0);
        __syncthreads();                           // buf^1 staged + all reads done
        cur ^= 1;
    }
    // ---- C write (fp8 for layer1, bf16 for layer2) ----
    #pragma unroll
    for (int i = 0; i < TM; i++) {
        #pragma unroll
        for (int j = 0; j < 4; j++) {
            #pragma unroll
            for (int r = 0; r < 4; r++) {
                int row = row0 + wr * (BM / 2) + i * 16 + quad * 4 + r;
                int col = col0 + wc * 64 + j * 16 + l15;
                if (row < M) {
                    float v = acc[i][j][r];
                    if (OMODE == 1)
                        ((u16*)C)[(size_t)row * N + col] = f2bf(v);
                    else
                        ((u8*)C)[(size_t)row * N + col] = f2fp8(v);
                }
            }
        }
    }
    // ---- fused per-row attention dots for this head ----
    float attS_r[4], attD_r[4];
    #pragma unroll
    for (int j = 0; j < 4; j++) {
        int col = wc * 64 + j * 16 + l15;
        attS_r[j] = attS[head * 128 + col];
        attD_r[j] = attD[head * 128 + col];
    }
    #pragma unroll
    for (int i = 0; i < TM; i++) {
        #pragma unroll
        for (int r = 0; r < 4; r++) {
            float ps = 0.f, pd = 0.f;
            #pragma unroll
            for (int j = 0; j < 4; j++) {
                float v = acc[i][j][r];
                ps = fmaf(v, attS_r[j], ps);
                pd = fmaf(v, attD_r[j], pd);
            }
            #pragma unroll
            for (int o = 1; o < 16; o <<= 1) {
                ps += __shfl_xor(ps, o, 64);
                pd += __shfl_xor(pd, o, 64);
            }
            if (l15 == 0) {
                int row = wr * (BM / 2) + i * 16 + quad * 4 + r;
                atomicAdd(&asb[row], ps);
                atomicAdd(&adb[row], pd);
            }
        }
    }
    __syncthreads();
    for (int t = tid; t < BM; t += 256) {
        int row = row0 + t;
        if (row < M) {
            as_out[(size_t)row * NHo + head] = asb[t];
            ad_out[(size_t)row * NHo + head] = adb[t];
        }
    }
}

// ---------- padded-bucket CSR fill (weights now computed inline in agg1) ----------
__global__ void fill_kernel(const int* __restrict__ ei, int E, int N,
                            int* __restrict__ cnt,
                            int* __restrict__ csr) {
    int j = blockIdx.x * 256 + threadIdx.x;
    if (j >= E + N) return;
    int s, d;
    if (j < E) { s = ei[j]; d = ei[E + j]; }
    else { s = j - E; d = j - E; }
    int pos = atomicAdd(&cnt[d], 1);
    if (pos >= CAP) return;   // safety net (never expected)
    csr[d * CAP + pos] = s;
}

// ---------- layer-1 softmax-aggregate + ELU ----------
// ONE WAVE per dst, padded bucket, GROUP=8 depth-2 ping-pong (R3 structure).
// Edge weights computed INLINE: as1 is a 640KB L2-resident table, so the
// per-edge 4B as1[s*8+h] load (in FETCH8, parallel with the row gather)
// replaces the old pw1 read from a 41MB HBM-spread array, and fill_kernel
// loses its 40MB of as/ad reads + pw1 writes entirely. leaky+exp (~6 VALU
// per edge) runs against 40% VALUBusy headroom. Pad edges are masked to
// weight 0 BEFORE den/acc; clamped garbage indices hit real finite rows.
#define A1_FETCH8(E0, Q, P)                                                   \
    {                                                                         \
        _Pragma("unroll")                                                     \
        for (int u = 0; u < 8; u++) {                                         \
            int e = (E0) + u;             /* e <= 63 < CAP always */          \
            int s = __builtin_amdgcn_readlane(idx, e);                        \
            s = s < 0 ? 0 : (s > NN - 1 ? NN - 1 : s);   /* SALU clamp */     \
            Q[u] = *(const uint4*)(h1q + (size_t)s * D1 + c0);                \
            P[u] = as1[s * NH + h];       /* L2-hit 4B; masked at PROC */     \
        }                                                                     \
        __builtin_amdgcn_sched_barrier(0);                                    \
    }
#define A1_PROC8(E0, Q, P)                                                    \
    {                                                                         \
        _Pragma("unroll")                                                     \
        for (int u = 0; u < 8; u++) {                                         \
            float ev = (P)[u] + adv;                                          \
            ev = ev > 0.f ? ev : 0.2f * ev;           /* LeakyReLU(0.2) */    \
            float pp = ((E0) + u < deg) ? __expf(ev) : 0.f;                   \
            den += pp;                                                        \
            f32x2 pv2 = {pp, pp};                                             \
            acc[0] += pv2 * __builtin_amdgcn_cvt_pk_f32_fp8((Q)[u].x, false); \
            acc[1] += pv2 * __builtin_amdgcn_cvt_pk_f32_fp8((Q)[u].x, true);  \
            acc[2] += pv2 * __builtin_amdgcn_cvt_pk_f32_fp8((Q)[u].y, false); \
            acc[3] += pv2 * __builtin_amdgcn_cvt_pk_f32_fp8((Q)[u].y, true);  \
            acc[4] += pv2 * __builtin_amdgcn_cvt_pk_f32_fp8((Q)[u].z, false); \
            acc[5] += pv2 * __builtin_amdgcn_cvt_pk_f32_fp8((Q)[u].z, true);  \
            acc[6] += pv2 * __builtin_amdgcn_cvt_pk_f32_fp8((Q)[u].w, false); \
            acc[7] += pv2 * __builtin_amdgcn_cvt_pk_f32_fp8((Q)[u].w, true);  \
        }                                                                     \
    }

__global__ __launch_bounds__(256) void agg1_kernel(const u8* __restrict__ h1q,
                                                   const float* __restrict__ as1,
                                                   const float* __restrict__ ad1,
                                                   const int* __restrict__ cnt,
                                                   const int* __restrict__ csr,
                                                   const float* __restrict__ bias1,
                                                   u16* __restrict__ x2) {
    const int tid = threadIdx.x;
    const int lane = tid & 63;
    const int dst = (blockIdx.x << 2) + (tid >> 6);
    const int c0 = lane * 16;               // 16 channels per lane
    const int h = lane >> 3;                // head (all 16 lane-channels same head)
    const int base = dst * CAP;

    int idx = csr[base + lane];                     // UNCLAMPED: || with cnt load
    const int deg = __builtin_amdgcn_readfirstlane(max(1, min(cnt[dst], CAP)));
    const float adv = ad1[dst * NH + h];            // per-head dst term

    f32x2 acc[8];
    #pragma unroll
    for (int k = 0; k < 8; k++) acc[k] = (f32x2){0.f, 0.f};
    float den = 0.f;

    const int nit = (deg + 7) >> 3;                 // groups of 8
    uint4 qa[8], qb[8];
    float pa[8], pb[8];
    A1_FETCH8(0, qa, pa)
    int g = 0;
    for (; g + 2 < nit; g += 2) {                   // ping-pong
        A1_FETCH8((g + 1) * 8, qb, pb)
        A1_PROC8(g * 8, qa, pa)
        A1_FETCH8((g + 2) * 8, qa, pa)
        A1_PROC8((g + 1) * 8, qb, pb)
    }
    if (g + 1 < nit) {
        A1_FETCH8((g + 1) * 8, qb, pb)
        A1_PROC8(g * 8, qa, pa)
        A1_PROC8((g + 1) * 8, qb, pb)
    } else {
        A1_PROC8(g * 8, qa, pa)
    }

    float inv = 1.f / (den + 1e-16f);
    u16 ov[16];
    #pragma unroll
    for (int k = 0; k < 8; k++) {
        float a0 = acc[k][0] * inv + bias1[c0 + 2 * k];
        float a1 = acc[k][1] * inv + bias1[c0 + 2 * k + 1];
        a0 = a0 > 0.f ? a0 : (__expf(a0) - 1.f);   // ELU (abs err ~1e-7, tol 0.03)
        a1 = a1 > 0.f ? a1 : (__expf(a1) - 1.f);
        ov[2 * k] = f2bf(a0);
        ov[2 * k + 1] = f2bf(a1);
    }
    *(uint4*)(x2 + (size_t)dst * D1 + c0) = *(const uint4*)ov;
    *(uint4*)(x2 + (size_t)dst * D1 + c0 + 8) = *(const uint4*)(ov + 8);
}

// ---------- layer-2 softmax-aggregate + log_softmax (inline edge weights) ----------
// ONE WAVE per dst; GROUP=8 depth-2 ping-pong + parallel setup loads.
// pl computed unconditionally (clamped idx -> finite as2 row); pad-edge
// mask applied at PROC via scalar (e<deg) select, off the exp chain.
#define A2_FETCH8(E0, Q)                                                      \
    {                                                                         \
        _Pragma("unroll")                                                     \
        for (int u = 0; u < 8; u++) {                                         \
            int s = __builtin_amdgcn_readlane(idx, (E0) + u);                 \
            s = s < 0 ? 0 : (s > NN - 1 ? NN - 1 : s);                        \
            Q[u] = *(const unsigned int*)(h2 + (size_t)s * C2 + lane2);       \
        }                                                                     \
        __builtin_amdgcn_sched_barrier(0);                                    \
    }
#define A2_PROC8(E0, Q)                                                       \
    {                                                                         \
        _Pragma("unroll")                                                     \
        for (int u = 0; u < 8; u++) {                                         \
            int e = (E0) + u;                                                 \
            float pp = (e < deg) ? __uint_as_float(__builtin_amdgcn_readlane( \
                                       __float_as_uint(pl), e))               \
                                 : 0.f;                                       \
            den += pp;                                                        \
            f32x2 pv2 = {pp, pp};                                             \
            f32x2 f = {__uint_as_float((Q)[u] << 16),                         \
                       __uint_as_float((Q)[u] & 0xFFFF0000u)};                \
            acc += pv2 * f;                                                   \
        }                                                                     \
    }

__global__ __launch_bounds__(256) void agg2_kernel(const u16* __restrict__ h2,
                                                   const float* __restrict__ as2,
                                                   const float* __restrict__ ad2,
                                                   const int* __restrict__ cnt,
                                                   const int* __restrict__ csr,
                                                   const float* __restrict__ bias2,
                                                   float* __restrict__ out) {
    const int tid = threadIdx.x;
    const int lane = tid & 63;
    const int dst = (blockIdx.x << 2) + (tid >> 6);
    const int base = dst * CAP;
    const int lane2 = lane * 2;

    int idx = csr[base + lane];                 // UNCLAMPED: || with cnt load
    const int deg = __builtin_amdgcn_readfirstlane(max(1, min(cnt[dst], CAP)));
    const float adv = ad2[dst];
    int idxc = idx < 0 ? 0 : (idx > NN - 1 ? NN - 1 : idx);
    float ev = as2[idxc] + adv;                 // random 4B within 80 KB (L2-hit)
    ev = ev > 0.f ? ev : 0.2f * ev;
    float pl = __expf(ev);                      // finite for any in-range row

    f32x2 acc = {0.f, 0.f};
    float den = 0.f;

    const int nit = (deg + 7) >> 3;
    unsigned int qa[8], qb[8];
    A2_FETCH8(0, qa)
    int g = 0;
    for (; g + 2 < nit; g += 2) {
        A2_FETCH8((g + 1) * 8, qb)
        A2_PROC8(g * 8, qa)
        A2_FETCH8((g + 2) * 8, qa)
        A2_PROC8((g + 1) * 8, qb)
    }
    if (g + 1 < nit) {
        A2_FETCH8((g + 1) * 8, qb)
        A2_PROC8(g * 8, qa)
        A2_PROC8((g + 1) * 8, qb)
    } else {
        A2_PROC8(g * 8, qa)
    }

    float inv = 1.f / (den + 1e-16f);
    float l0 = acc[0] * inv + bias2[lane2];
    float l1 = acc[1] * inv + bias2[lane2 + 1];
    // log_softmax over the wave's 128 channels
    float m = bred_max(fmaxf(l0, l1));
    float ex = bred_sum(__expf(l0 - m) + __expf(l1 - m));
    float lse = m + __logf(ex);
    float2 ov = {l0 - lse, l1 - lse};
    *(float2*)(out + (size_t)dst * C2 + lane2) = ov;
}

extern "C" void kernel_launch(void* const* d_in, const int* in_sizes, int n_in,
                              void* d_out, int out_size, void* d_ws, size_t ws_size,
                              hipStream_t stream) {
    const float* x        = (const float*)d_in[0];
    const int*   ei       = (const int*)d_in[1];
    const float* W1       = (const float*)d_in[2];
    const float* att_src1 = (const float*)d_in[3];
    const float* att_dst1 = (const float*)d_in[4];
    const float* bias1    = (const float*)d_in[5];
    const float* W2       = (const float*)d_in[6];
    const float* att_src2 = (const float*)d_in[7];
    const float* att_dst2 = (const float*)d_in[8];
    const float* bias2    = (const float*)d_in[9];
    float* out = (float*)d_out;
    const int E = in_sizes[1] / 2;

    char* ws = (char*)d_ws;
    size_t off = 0;
    auto alloc = [&](size_t b) {
        void* p = ws + off;
        off += (b + 255) & ~(size_t)255;
        return p;
    };
    u8*  h1q  = (u8*)alloc((size_t)NN * D1);
    u16* x2   = (u16*)alloc((size_t)NN * D1 * 2);
    u16* h2   = (u16*)alloc((size_t)NN * C2 * 2);
    u16* xb   = (u16*)alloc((size_t)NN * FIN * 2);
    u16* w1t  = (u16*)alloc((size_t)D1 * FIN * 2);
    u16* w2t  = (u16*)alloc((size_t)C2 * D1 * 2);
    float* as1 = (float*)alloc((size_t)NN * NH * 4);
    float* ad1 = (float*)alloc((size_t)NN * NH * 4);
    float* as2 = (float*)alloc((size_t)NN * 4);
    float* ad2 = (float*)alloc((size_t)NN * 4);
    int* cnt  = (int*)alloc((size_t)NN * 4);
    int* csr  = (int*)alloc((size_t)NN * CAP * 4);

    // fused prep: cast x, transpose W1/W2, zero cnt
    const int PREP_BLOCKS = 5000 + 256 + 128 + (NN + 255) / 256;
    prep_kernel<<<PREP_BLOCKS, 256, 0, stream>>>(x, xb, W1, w1t, W2, w2t, cnt);

    // layer 1 GEMM: h1q fp8 + fused per-head as1/ad1
    gemm_mfma<128, 2><<<dim3((NN + 127) / 128, D1 / 128), 256, 0, stream>>>(
        xb, w1t, h1q, att_src1, att_dst1, as1, ad1, NH, NN, D1, FIN);
    fill_kernel<<<(E + NN + 255) / 256, 256, 0, stream>>>(ei, E, NN, cnt, csr);
    // 1 wave per dst: 20000 waves = 5000 blocks
    agg1_kernel<<<(NN + 3) / 4, 256, 0, stream>>>(h1q, as1, ad1, cnt, csr, bias1, x2);
    // layer 2 GEMM: h2 bf16 + fused as2/ad2
    gemm_mfma<64, 1><<<dim3((NN + 63) / 64, C2 / 128), 256, 0, stream>>>(
        x2, w2t, h2, att_src2, att_dst2, as2, ad2, 1, NN, C2, D1);
    agg2_kernel<<<(NN + 3) / 4, 256, 0, stream>>>(h2, as2, ad2, cnt, csr, bias2, out);
}